// Round 16
// baseline (345.153 us; speedup 1.0000x reference)
//
#include <hip/hip_runtime.h>
#include <hip/hip_bf16.h>
#include <cstdint>

typedef _Float16 h8 __attribute__((ext_vector_type(8)));
typedef _Float16 h4 __attribute__((ext_vector_type(4)));
typedef float    f4 __attribute__((ext_vector_type(4)));
typedef float    fx16 __attribute__((ext_vector_type(16)));

// Dims: B=16, Cin=256, Ch=128, Br=8, H=W=64, 4096 px/image, 65536 px total.
// ws layout (23 MB):
//   hr   @ 0          16,777,216 B  (f16 [65536 px][128 ch])
//   W1r  @ 16777216    4,718,592 B  (f16 [ci8][tap9][g8][128c][32ch slot-XOR])
//   W2r  @ 21495808      524,288 B  (f16 [g][kc4][256co][32ch])
//   sel1 @ 22020096    2,097,152 B  (f32 [b][g][4096])
//
// LDS involution: 16B slot s at row r lives at slot s ^ ((r>>1)&3).
//
// conv1 (R16) = R15's verified counted-vmcnt template, chunk size 2->4
// experts (parameter change) + T5 setprio:
//   144 chunks of 32KB, 2 phases/tap, wt[3] rotation, buf = (2kx+gp)%3
//   (compile-time in unrolled kx/gp loops).
//   per phase P: s_barrier ; s_waitcnt vmcnt(4) ; sched_barrier(0) ;
//                ds_read 16 A-frags ; setprio(1) 32 MFMA setprio(0) ;
//                stage_w(P+2) [4 GLD16, stay in flight]
// vmcnt ledger: at top of P outstanding = stage(P)+stage(P+1) = 8; vmcnt(4)
// retires the OLDEST 4 = stage(P) (m135). Final phase (P=143): vmcnt(0).
// Race ledger: buf of stage(P+2) last read at phase P-1; top-of-P s_barrier
// separates. __syncthreads only at ci boundary (xs publication).

#define GLD16(src, dst) __builtin_amdgcn_global_load_lds( \
    (const __attribute__((address_space(1))) void*)(src), \
    (__attribute__((address_space(3))) void*)(dst), 16, 0, 0)

// ---------------- prep_w: fp32 -> f16 repack, output-major ----------------
__global__ __launch_bounds__(256) void prep_w_k(const float* __restrict__ W1,
        const float* __restrict__ W2, _Float16* __restrict__ W1r,
        _Float16* __restrict__ W2r) {
    int o8 = blockIdx.x * 256 + threadIdx.x;   // one h8 output group per thread
    if (o8 < 294912) {
        int sq = o8 & 3;
        int c  = (o8 >> 2) & 127;
        int g  = (o8 >> 9) & 7;
        int tk = o8 >> 12;                 // cik*9 + tap
        int tap = tk % 9, cik = tk / 9;
        int s = sq ^ ((c >> 1) & 3);
        int ci0 = cik * 32 + s * 8;
        const float* src = W1 + ((size_t)(g * 128 + c) * 256 + ci0) * 9 + tap;
        h8 v;
        #pragma unroll
        for (int e = 0; e < 8; ++e) v[e] = (_Float16)src[e * 9];
        *(h8*)(W1r + (size_t)o8 * 8) = v;
    } else {
        int ow = o8 - 294912;              // W2r h8 groups: 32768
        int sg = ow & 3;
        int co = (ow >> 2) & 255;
        int kc = (ow >> 10) & 3;
        int g  = ow >> 12;
        const float* src = W2 + ((size_t)(g * 256 + co) * 128) + kc * 32 + sg * 8;
        h8 v;
        #pragma unroll
        for (int e = 0; e < 8; ++e) v[e] = (_Float16)src[e];
        *(h8*)(W2r + (size_t)ow * 8) = v;
    }
}

// ---------------- prep_x: sel1 softmax only ----------------
__global__ __launch_bounds__(256) void prep_x_k(const float* __restrict__ x,
        const float* __restrict__ Wc1, const float* __restrict__ bc1,
        float* __restrict__ sel1) {
    __shared__ float wc[2048];            // Wc1 [8][256]
    int t = threadIdx.x;
    for (int i = t; i < 2048; i += 256) wc[i] = Wc1[i];
    __syncthreads();
    int pix = blockIdx.x * 256 + t;       // b*4096 + p
    int b = pix >> 12, p = pix & 4095;
    const float* xp = x + (size_t)b * 1048576 + p;
    float lg[8] = {0.f,0.f,0.f,0.f,0.f,0.f,0.f,0.f};
    for (int c = 0; c < 256; ++c) {
        float v = fmaxf(xp[(size_t)c * 4096], 0.f);
        #pragma unroll
        for (int g = 0; g < 8; ++g) lg[g] += wc[g * 256 + c] * v;
    }
    float m = -1e30f;
    #pragma unroll
    for (int g = 0; g < 8; ++g) { lg[g] += bc1[g]; m = fmaxf(m, lg[g]); }
    float sum = 0.f;
    #pragma unroll
    for (int g = 0; g < 8; ++g) { lg[g] = __expf(lg[g] - m); sum += lg[g]; }
    float inv = 1.f / sum;
    #pragma unroll
    for (int g = 0; g < 8; ++g)
        sel1[(size_t)(b * 8 + g) * 4096 + p] = lg[g] * inv;
}

// ---------------- conv1: switched 3x3, 128c x 256px, counted-vmcnt pipe ----
__global__ __launch_bounds__(512, 2) void conv1_k(const float* __restrict__ x,
        const _Float16* __restrict__ W1r, const float* __restrict__ sel1,
        const float* __restrict__ b1, _Float16* __restrict__ hr) {
    __shared__ _Float16 wt[3][16384];     // 3 x 32KB: [g4][128c][32ch slot-XOR]
    __shared__ _Float16 xs[12296];        // [6 rows][64 col][32 ch slot-XOR] + zero @12288
    int t = threadIdx.x;
    int b = blockIdx.y, yt = blockIdx.x;  // yt: group of 4 output rows
    int y0 = yt * 4;
    int w = t >> 6, l = t & 63;
    int wm = w >> 2, wn = w & 3;          // wm: 64-ch half, wn: output row (64px)
    int l31 = l & 31, kq2 = l >> 5;
    if (t < 8) xs[12288 + t] = (_Float16)0.f;   // zero slot

    fx16 acc[2][2];                       // [m][nf]
    #pragma unroll
    for (int m = 0; m < 2; ++m)
        #pragma unroll
        for (int n = 0; n < 2; ++n)
            #pragma unroll
            for (int e = 0; e < 16; ++e) acc[m][n][e] = 0.f;

    auto stage_w = [&](int P, int bi) {   // one 4-expert chunk (32 KB)
        const _Float16* srcw = W1r + (size_t)P * 16384 + t * 8;
        _Float16* dw = wt[bi] + t * 8;
        #pragma unroll
        for (int it = 0; it < 4; ++it)
            GLD16(srcw + it * 4096, dw + it * 4096);
    };

    // lane constants (R6-identical)
    int px[2];
    #pragma unroll
    for (int nf = 0; nf < 2; ++nf) px[nf] = wn * 64 + nf * 32 + l31;
    bool e0 = (l31 == 0), e63 = (l31 == 31);
    int afo[2][2];
    #pragma unroll
    for (int m = 0; m < 2; ++m)
        #pragma unroll
        for (int kc = 0; kc < 2; ++kc) {
            int c = wm * 64 + m * 32 + l31;
            afo[m][kc] = c * 32 + (((kc * 2 + kq2) ^ ((c >> 1) & 3)) * 8);
        }
    int ba[2][3][2];
    #pragma unroll
    for (int nf = 0; nf < 2; ++nf)
        #pragma unroll
        for (int kx = 0; kx < 3; ++kx) {
            int rz = px[nf] + kx - 1;
            #pragma unroll
            for (int kc = 0; kc < 2; ++kc)
                ba[nf][kx][kc] = rz * 32 + (((kc * 2 + kq2) ^ ((rz >> 1) & 3)) * 8);
        }
    h8 selv[2];
    #pragma unroll
    for (int nf = 0; nf < 2; ++nf)
        #pragma unroll
        for (int g = 0; g < 8; ++g)
            selv[nf][g] = (_Float16)sel1[(size_t)(b * 8 + g) * 4096 + yt * 256 + px[nf]];

    h8 bfr[2][2];                         // B-frags for current tap [nf][kc]

    // prologue: chunks 0,1 into bufs 0,1 (in flight)
    stage_w(0, 0);
    stage_w(1, 1);

    #pragma unroll 1
    for (int ci = 0; ci < 8; ++ci) {
        // stage relu(x): previous xs readers all completed >= 1 phase-barrier ago
        if (t < 384) {
            int r = t >> 6, col = t & 63;
            int rc = r * 64 + col;
            int yi = y0 - 1 + r;
            _Float16* dx = xs + rc * 32;
            int rx = (rc >> 1) & 3;
            if (yi >= 0 && yi < 64) {
                const float* xp = x + ((size_t)(b * 256 + ci * 32)) * 4096 + yi * 64 + col;
                float v[32];
                #pragma unroll
                for (int c2 = 0; c2 < 32; ++c2)
                    v[c2] = fmaxf(xp[(size_t)c2 * 4096], 0.f);
                #pragma unroll
                for (int qq = 0; qq < 4; ++qq) {
                    h8 hv;
                    #pragma unroll
                    for (int e = 0; e < 8; ++e) hv[e] = (_Float16)v[qq * 8 + e];
                    *(h8*)(dx + (qq ^ rx) * 8) = hv;   // involution: read undoes it
                }
            } else {
                const h8 HZ = {};
                #pragma unroll
                for (int qq = 0; qq < 4; ++qq)
                    *(h8*)(dx + (qq ^ rx) * 8) = HZ;
            }
        }
        __syncthreads();                  // publish xs (full drain, 1x per ci)
        #pragma unroll 1
        for (int ky = 0; ky < 3; ++ky) {
            #pragma unroll
            for (int kx = 0; kx < 3; ++kx) {
                int tap = ci * 9 + ky * 3 + kx;
                // B-frags for this tap (xs stable within ci)
                #pragma unroll
                for (int nf = 0; nf < 2; ++nf)
                    #pragma unroll
                    for (int kc = 0; kc < 2; ++kc) {
                        int a = ba[nf][kx][kc] + ky * 2048;
                        if (kx == 0 && nf == 0) a = e0 ? 12288 : a;
                        if (kx == 2 && nf == 1) a = e63 ? 12288 : a;
                        bfr[nf][kc] = *(const h8*)(xs + a);
                    }
                #pragma unroll
                for (int gp = 0; gp < 2; ++gp) {
                    int P = tap * 2 + gp;
                    __builtin_amdgcn_s_barrier();      // raw barrier, no drain
                    if (P >= 143) {                    // final: nothing behind
                        asm volatile("s_waitcnt vmcnt(0)" ::: "memory");
                    } else {                           // counted: retire stage(P)
                        asm volatile("s_waitcnt vmcnt(4)" ::: "memory");
                    }
                    __builtin_amdgcn_sched_barrier(0);
                    const _Float16* wp = wt[(2 * kx + gp) % 3];
                    __builtin_amdgcn_s_setprio(1);
                    #pragma unroll
                    for (int gl = 0; gl < 4; ++gl) {
                        #pragma unroll
                        for (int kc = 0; kc < 2; ++kc) {
                            h8 a0 = *(const h8*)(wp + gl * 4096 + afo[0][kc]);
                            h8 a1 = *(const h8*)(wp + gl * 4096 + afo[1][kc]);
                            #pragma unroll
                            for (int nf = 0; nf < 2; ++nf) {
                                h8 bs = bfr[nf][kc] * selv[nf][gp * 4 + gl];
                                acc[0][nf] = __builtin_amdgcn_mfma_f32_32x32x16_f16(
                                    a0, bs, acc[0][nf], 0, 0, 0);
                                acc[1][nf] = __builtin_amdgcn_mfma_f32_32x32x16_f16(
                                    a1, bs, acc[1][nf], 0, 0, 0);
                            }
                        }
                    }
                    __builtin_amdgcn_s_setprio(0);
                    if (P < 142) stage_w(P + 2, (2 * kx + gp + 2) % 3);
                }
            }
        }
    }
    // epilogue: + b1, relu, f16, NHWC hr
    // C/D (32x32): col=lane&31, row=(reg&3)+8*(reg>>2)+4*(lane>>5)
    #pragma unroll
    for (int m = 0; m < 2; ++m)
        #pragma unroll
        for (int nf = 0; nf < 2; ++nf) {
            size_t pg = ((size_t)(b * 4096 + yt * 256 + px[nf])) * 128;
            #pragma unroll
            for (int q = 0; q < 4; ++q) {
                int c0 = wm * 64 + m * 32 + q * 8 + kq2 * 4;
                f4 bb = *(const f4*)(b1 + c0);
                h4 hv;
                #pragma unroll
                for (int r = 0; r < 4; ++r)
                    hv[r] = (_Float16)fmaxf(acc[m][nf][q * 4 + r] + bb[r], 0.f);
                *(h4*)(hr + pg + c0) = hv;
            }
        }
}

// ---------------- conv2: switched 1x1 + fused sel2 softmax + residual ------
__global__ __launch_bounds__(256, 2) void conv2_k(const _Float16* __restrict__ hr,
        const _Float16* __restrict__ W2r, const float* __restrict__ Wc2,
        const float* __restrict__ bc2, const float* __restrict__ b2,
        const float* __restrict__ x, float* __restrict__ out) {
    __shared__ _Float16 hs[64 * 128];        // [64 px][128 ch] swizzled (16KB)
    __shared__ _Float16 wt[2][256 * 32];     // dbuf [256 co][32 ch] swizzled (32KB)
    __shared__ float wc[1024];               // Wc2 [8][128] (4KB)
    __shared__ float red[2048];              // [64 px][8 g][4 strip] (8KB)
    __shared__ float selw[512];              // [64 px][8 g] (2KB)
    int t = threadIdx.x;
    int bid = blockIdx.x;
    int b = bid >> 6, p0 = (bid & 63) * 64;
    int l = t & 63, w = t >> 6;
    int wm = w >> 1, wn = w & 1;
    int l15 = l & 15, sl = l >> 4;
    int swl = (l15 & 7) << 3;
    const f4 FZ = {0.f, 0.f, 0.f, 0.f};
    f4 acce[8][2], accf[8][2];
    #pragma unroll
    for (int m = 0; m < 8; ++m)
        #pragma unroll
        for (int n = 0; n < 2; ++n) { acce[m][n] = FZ; accf[m][n] = FZ; }
    for (int i = t; i < 1024; i += 256) wc[i] = Wc2[i];
    {   // stage h tile (swizzled)
        int px = t >> 2, qq = t & 3;
        const _Float16* src = hr + (size_t)(b * 4096 + p0 + px) * 128 + qq * 32;
        #pragma unroll
        for (int u = 0; u < 4; ++u)
            *(h8*)(hs + ((px * 128 + qq * 32 + u * 8) ^ ((px & 7) << 3)))
                = *(const h8*)(src + u * 8);
    }
    h8 wr[4];
    auto load_w = [&](int T) {
        const _Float16* srcw = W2r + (size_t)T * 8192;
        #pragma unroll
        for (int it = 0; it < 4; ++it)
            wr[it] = *(const h8*)(srcw + (size_t)(it * 256 + t) * 8);
    };
    auto write_w = [&](int bf) {
        #pragma unroll
        for (int it = 0; it < 4; ++it) {
            int cc = it * 256 + t;
            int c = cc >> 2, q = cc & 3;
            *(h8*)(wt[bf] + ((c * 32 + q * 8) ^ ((c & 7) << 3))) = wr[it];
        }
    };
    load_w(0);
    __syncthreads();                      // publish hs + wc
    {   // fused sel2: partial logits (4 threads/px x 32 ch)
        int px = t >> 2, qq = t & 3;
        float lg[8] = {0.f,0.f,0.f,0.f,0.f,0.f,0.f,0.f};
        #pragma unroll
        for (int u = 0; u < 4; ++u) {
            h8 v = *(const h8*)(hs + ((px * 128 + qq * 32 + u * 8) ^ ((px & 7) << 3)));
            #pragma unroll
            for (int e = 0; e < 8; ++e) {
                float f = (float)v[e];
                int c = qq * 32 + u * 8 + e;
                #pragma unroll
                for (int g = 0; g < 8; ++g) lg[g] += wc[g * 128 + c] * f;
            }
        }
        #pragma unroll
        for (int g = 0; g < 8; ++g) red[(px * 8 + g) * 4 + qq] = lg[g];
    }
    __syncthreads();
    if (t < 64) {                         // softmax per pixel
        float lg[8]; float m = -1e30f;
        #pragma unroll
        for (int g = 0; g < 8; ++g) {
            lg[g] = red[(t*8+g)*4+0] + red[(t*8+g)*4+1]
                  + red[(t*8+g)*4+2] + red[(t*8+g)*4+3] + bc2[g];
            m = fmaxf(m, lg[g]);
        }
        float sum = 0.f;
        #pragma unroll
        for (int g = 0; g < 8; ++g) { lg[g] = __expf(lg[g] - m); sum += lg[g]; }
        float inv = 1.f / sum;
        #pragma unroll
        for (int g = 0; g < 8; ++g) selw[t * 8 + g] = lg[g] * inv;
    }
    write_w(0);                           // wt[0] LDS writes (no reader yet)
    __syncthreads();                      // publish selw + wt[0]
    float selr[8][2];
    #pragma unroll
    for (int g = 0; g < 8; ++g)
        #pragma unroll
        for (int n = 0; n < 2; ++n)
            selr[g][n] = selw[(wn * 32 + n * 16 + l15) * 8 + g];
    int afo[8];
    #pragma unroll
    for (int m = 0; m < 8; ++m) {
        int c = wm * 128 + m * 16 + l15;
        afo[m] = ((c * 32 + sl * 8) ^ swl);
    }
    int buf = 0;
    #pragma unroll 1
    for (int T = 0; T < 32; ++T) {          // T = g*4 + kchunk
        bool hn = (T < 31);
        if (hn) load_w(T + 1);
        __syncthreads();   // publishes wt[buf]
        int kc = (T & 3) * 32;
        h8 bfv[2];
        #pragma unroll
        for (int n = 0; n < 2; ++n) {
            int px = wn * 32 + n * 16 + l15;
            bfv[n] = *(const h8*)(hs + ((px * 128 + kc + sl * 8) ^ ((px & 7) << 3)));
        }
        #pragma unroll
        for (int m = 0; m < 8; ++m) {
            h8 af = *(const h8*)(wt[buf] + afo[m]);
            #pragma unroll
            for (int n = 0; n < 2; ++n)
                acce[m][n] = __builtin_amdgcn_mfma_f32_16x16x32_f16(
                    af, bfv[n], acce[m][n], 0, 0, 0);
        }
        if ((T & 3) == 3) {
            int g = T >> 2;
            #pragma unroll
            for (int n = 0; n < 2; ++n)
                #pragma unroll
                for (int m = 0; m < 8; ++m) {
                    accf[m][n] += selr[g][n] * acce[m][n];
                    acce[m][n] = FZ;
                }
        }
        if (hn) write_w(buf ^ 1);
        buf ^= 1;
    }
    // epilogue: + b2 + residual x, fp32 NCHW out
    #pragma unroll
    for (int m = 0; m < 8; ++m) {
        int c0 = wm * 128 + m * 16 + sl * 4;
        f4 bb = *(const f4*)(b2 + c0);
        #pragma unroll
        for (int n = 0; n < 2; ++n) {
            int px = wn * 32 + n * 16 + l15;
            size_t o = (size_t)(b * 256 + c0) * 4096 + p0 + px;
            #pragma unroll
            for (int r = 0; r < 4; ++r)
                out[o + (size_t)r * 4096] = accf[m][n][r] + bb[r] + x[o + (size_t)r * 4096];
        }
    }
}

extern "C" void kernel_launch(void* const* d_in, const int* in_sizes, int n_in,
                              void* d_out, int out_size, void* d_ws, size_t ws_size,
                              hipStream_t stream) {
    const float* x   = (const float*)d_in[0];
    const float* W1  = (const float*)d_in[1];
    const float* b1  = (const float*)d_in[2];
    const float* Wc1 = (const float*)d_in[3];
    const float* bc1 = (const float*)d_in[4];
    const float* W2  = (const float*)d_in[5];
    const float* b2  = (const float*)d_in[6];
    const float* Wc2 = (const float*)d_in[7];
    const float* bc2 = (const float*)d_in[8];
    float* out = (float*)d_out;
    char* ws = (char*)d_ws;
    _Float16* hr  = (_Float16*)(ws);                   // 16,777,216 B
    _Float16* W1r = (_Float16*)(ws + 16777216);        //  4,718,592 B
    _Float16* W2r = (_Float16*)(ws + 21495808);        //    524,288 B
    float* sel1   = (float*)(ws + 22020096);           //  2,097,152 B

    hipLaunchKernelGGL(prep_w_k, dim3(1280), dim3(256), 0, stream, W1, W2, W1r, W2r);
    hipLaunchKernelGGL(prep_x_k, dim3(256), dim3(256), 0, stream, x, Wc1, bc1, sel1);
    hipLaunchKernelGGL(conv1_k, dim3(16, 16), dim3(512), 0, stream, x, W1r, sel1, b1, hr);
    hipLaunchKernelGGL(conv2_k, dim3(1024), dim3(256), 0, stream, hr, W2r, Wc2, bc2, b2, x, out);
}

// Round 17
// 334.926 us; speedup vs baseline: 1.0305x; 1.0305x over previous
//
#include <hip/hip_runtime.h>
#include <hip/hip_bf16.h>
#include <cstdint>

typedef _Float16 h8 __attribute__((ext_vector_type(8)));
typedef _Float16 h4 __attribute__((ext_vector_type(4)));
typedef float    f4 __attribute__((ext_vector_type(4)));
typedef float    fx16 __attribute__((ext_vector_type(16)));

// Dims: B=16, Cin=256, Ch=128, Br=8, H=W=64, 4096 px/image, 65536 px total.
// ws layout (23 MB):
//   hr   @ 0          16,777,216 B  (f16 [65536 px][128 ch])
//   W1r  @ 16777216    4,718,592 B  (f16 [ci8][tap9][g8][128c][32ch slot-XOR])
//   W2r  @ 21495808      524,288 B  (f16 [g][kc4][256co][32ch slot-XOR])
//   sel1 @ 22020096    2,097,152 B  (f32 [b][g][4096])
//
// LDS involution (both convs): 16B slot s at row r lives at slot s ^ ((r>>1)&3).
//
// conv1 (frozen, R16): 144 chunks of 4 experts (32KB), wt[3] rotation,
// counted vmcnt(4), setprio. conv2 (R17): same template — GLD16 staging of
// pre-swizzled W2r into wt[3] (16KB chunks), counted vmcnt(4), raw s_barrier,
// setprio; fused sel2 softmax prologue unchanged.
// prep_x (R17): grid 512, 128px/block, 2 threads/px (c-halves), LDS combine.

#define GLD16(src, dst) __builtin_amdgcn_global_load_lds( \
    (const __attribute__((address_space(1))) void*)(src), \
    (__attribute__((address_space(3))) void*)(dst), 16, 0, 0)

// ---------------- prep_w: fp32 -> f16 repack, output-major ----------------
__global__ __launch_bounds__(256) void prep_w_k(const float* __restrict__ W1,
        const float* __restrict__ W2, _Float16* __restrict__ W1r,
        _Float16* __restrict__ W2r) {
    int o8 = blockIdx.x * 256 + threadIdx.x;   // one h8 output group per thread
    if (o8 < 294912) {
        int sq = o8 & 3;
        int c  = (o8 >> 2) & 127;
        int g  = (o8 >> 9) & 7;
        int tk = o8 >> 12;                 // cik*9 + tap
        int tap = tk % 9, cik = tk / 9;
        int s = sq ^ ((c >> 1) & 3);
        int ci0 = cik * 32 + s * 8;
        const float* src = W1 + ((size_t)(g * 128 + c) * 256 + ci0) * 9 + tap;
        h8 v;
        #pragma unroll
        for (int e = 0; e < 8; ++e) v[e] = (_Float16)src[e * 9];
        *(h8*)(W1r + (size_t)o8 * 8) = v;
    } else {
        int ow = o8 - 294912;              // W2r h8 groups: 32768
        int sq = ow & 3;                   // physical 16B slot
        int co = (ow >> 2) & 255;
        int kc = (ow >> 10) & 3;
        int g  = ow >> 12;
        int s = sq ^ ((co >> 1) & 3);      // logical 8-half group (involution)
        const float* src = W2 + ((size_t)(g * 256 + co) * 128) + kc * 32 + s * 8;
        h8 v;
        #pragma unroll
        for (int e = 0; e < 8; ++e) v[e] = (_Float16)src[e];
        *(h8*)(W2r + (size_t)ow * 8) = v;
    }
}

// ---------------- prep_x: sel1 softmax, 2 threads/px ----------------
__global__ __launch_bounds__(256) void prep_x_k(const float* __restrict__ x,
        const float* __restrict__ Wc1, const float* __restrict__ bc1,
        float* __restrict__ sel1) {
    __shared__ float wc[2048];            // Wc1 [8][256]
    __shared__ float red[1024];           // [128 px][8 g] partial from upper half
    int t = threadIdx.x;
    for (int i = t; i < 2048; i += 256) wc[i] = Wc1[i];
    __syncthreads();
    int pxl = t & 127, ch = t >> 7;       // ch: c-half 0/1
    int pix = blockIdx.x * 128 + pxl;
    int b = pix >> 12, p = pix & 4095;
    const float* xp = x + (size_t)b * 1048576 + (size_t)ch * 524288 + p;
    float lg[8] = {0.f,0.f,0.f,0.f,0.f,0.f,0.f,0.f};
    for (int c = 0; c < 128; ++c) {
        float v = fmaxf(xp[(size_t)c * 4096], 0.f);
        #pragma unroll
        for (int g = 0; g < 8; ++g) lg[g] += wc[g * 256 + ch * 128 + c] * v;
    }
    if (ch)
        #pragma unroll
        for (int g = 0; g < 8; ++g) red[pxl * 8 + g] = lg[g];
    __syncthreads();
    if (!ch) {
        float m = -1e30f;
        #pragma unroll
        for (int g = 0; g < 8; ++g) {
            lg[g] += red[pxl * 8 + g] + bc1[g];
            m = fmaxf(m, lg[g]);
        }
        float sum = 0.f;
        #pragma unroll
        for (int g = 0; g < 8; ++g) { lg[g] = __expf(lg[g] - m); sum += lg[g]; }
        float inv = 1.f / sum;
        #pragma unroll
        for (int g = 0; g < 8; ++g)
            sel1[(size_t)(b * 8 + g) * 4096 + p] = lg[g] * inv;
    }
}

// ---------------- conv1: FROZEN R16. switched 3x3, counted-vmcnt pipe ----
__global__ __launch_bounds__(512, 2) void conv1_k(const float* __restrict__ x,
        const _Float16* __restrict__ W1r, const float* __restrict__ sel1,
        const float* __restrict__ b1, _Float16* __restrict__ hr) {
    __shared__ _Float16 wt[3][16384];     // 3 x 32KB: [g4][128c][32ch slot-XOR]
    __shared__ _Float16 xs[12296];        // [6 rows][64 col][32 ch slot-XOR] + zero @12288
    int t = threadIdx.x;
    int b = blockIdx.y, yt = blockIdx.x;  // yt: group of 4 output rows
    int y0 = yt * 4;
    int w = t >> 6, l = t & 63;
    int wm = w >> 2, wn = w & 3;          // wm: 64-ch half, wn: output row (64px)
    int l31 = l & 31, kq2 = l >> 5;
    if (t < 8) xs[12288 + t] = (_Float16)0.f;   // zero slot

    fx16 acc[2][2];                       // [m][nf]
    #pragma unroll
    for (int m = 0; m < 2; ++m)
        #pragma unroll
        for (int n = 0; n < 2; ++n)
            #pragma unroll
            for (int e = 0; e < 16; ++e) acc[m][n][e] = 0.f;

    auto stage_w = [&](int P, int bi) {   // one 4-expert chunk (32 KB)
        const _Float16* srcw = W1r + (size_t)P * 16384 + t * 8;
        _Float16* dw = wt[bi] + t * 8;
        #pragma unroll
        for (int it = 0; it < 4; ++it)
            GLD16(srcw + it * 4096, dw + it * 4096);
    };

    // lane constants (R6-identical)
    int px[2];
    #pragma unroll
    for (int nf = 0; nf < 2; ++nf) px[nf] = wn * 64 + nf * 32 + l31;
    bool e0 = (l31 == 0), e63 = (l31 == 31);
    int afo[2][2];
    #pragma unroll
    for (int m = 0; m < 2; ++m)
        #pragma unroll
        for (int kc = 0; kc < 2; ++kc) {
            int c = wm * 64 + m * 32 + l31;
            afo[m][kc] = c * 32 + (((kc * 2 + kq2) ^ ((c >> 1) & 3)) * 8);
        }
    int ba[2][3][2];
    #pragma unroll
    for (int nf = 0; nf < 2; ++nf)
        #pragma unroll
        for (int kx = 0; kx < 3; ++kx) {
            int rz = px[nf] + kx - 1;
            #pragma unroll
            for (int kc = 0; kc < 2; ++kc)
                ba[nf][kx][kc] = rz * 32 + (((kc * 2 + kq2) ^ ((rz >> 1) & 3)) * 8);
        }
    h8 selv[2];
    #pragma unroll
    for (int nf = 0; nf < 2; ++nf)
        #pragma unroll
        for (int g = 0; g < 8; ++g)
            selv[nf][g] = (_Float16)sel1[(size_t)(b * 8 + g) * 4096 + yt * 256 + px[nf]];

    h8 bfr[2][2];                         // B-frags for current tap [nf][kc]

    // prologue: chunks 0,1 into bufs 0,1 (in flight)
    stage_w(0, 0);
    stage_w(1, 1);

    #pragma unroll 1
    for (int ci = 0; ci < 8; ++ci) {
        // stage relu(x): previous xs readers all completed >= 1 phase-barrier ago
        if (t < 384) {
            int r = t >> 6, col = t & 63;
            int rc = r * 64 + col;
            int yi = y0 - 1 + r;
            _Float16* dx = xs + rc * 32;
            int rx = (rc >> 1) & 3;
            if (yi >= 0 && yi < 64) {
                const float* xp = x + ((size_t)(b * 256 + ci * 32)) * 4096 + yi * 64 + col;
                float v[32];
                #pragma unroll
                for (int c2 = 0; c2 < 32; ++c2)
                    v[c2] = fmaxf(xp[(size_t)c2 * 4096], 0.f);
                #pragma unroll
                for (int qq = 0; qq < 4; ++qq) {
                    h8 hv;
                    #pragma unroll
                    for (int e = 0; e < 8; ++e) hv[e] = (_Float16)v[qq * 8 + e];
                    *(h8*)(dx + (qq ^ rx) * 8) = hv;   // involution: read undoes it
                }
            } else {
                const h8 HZ = {};
                #pragma unroll
                for (int qq = 0; qq < 4; ++qq)
                    *(h8*)(dx + (qq ^ rx) * 8) = HZ;
            }
        }
        __syncthreads();                  // publish xs (full drain, 1x per ci)
        #pragma unroll 1
        for (int ky = 0; ky < 3; ++ky) {
            #pragma unroll
            for (int kx = 0; kx < 3; ++kx) {
                int tap = ci * 9 + ky * 3 + kx;
                // B-frags for this tap (xs stable within ci)
                #pragma unroll
                for (int nf = 0; nf < 2; ++nf)
                    #pragma unroll
                    for (int kc = 0; kc < 2; ++kc) {
                        int a = ba[nf][kx][kc] + ky * 2048;
                        if (kx == 0 && nf == 0) a = e0 ? 12288 : a;
                        if (kx == 2 && nf == 1) a = e63 ? 12288 : a;
                        bfr[nf][kc] = *(const h8*)(xs + a);
                    }
                #pragma unroll
                for (int gp = 0; gp < 2; ++gp) {
                    int P = tap * 2 + gp;
                    __builtin_amdgcn_s_barrier();      // raw barrier, no drain
                    if (P >= 143) {                    // final: nothing behind
                        asm volatile("s_waitcnt vmcnt(0)" ::: "memory");
                    } else {                           // counted: retire stage(P)
                        asm volatile("s_waitcnt vmcnt(4)" ::: "memory");
                    }
                    __builtin_amdgcn_sched_barrier(0);
                    const _Float16* wp = wt[(2 * kx + gp) % 3];
                    __builtin_amdgcn_s_setprio(1);
                    #pragma unroll
                    for (int gl = 0; gl < 4; ++gl) {
                        #pragma unroll
                        for (int kc = 0; kc < 2; ++kc) {
                            h8 a0 = *(const h8*)(wp + gl * 4096 + afo[0][kc]);
                            h8 a1 = *(const h8*)(wp + gl * 4096 + afo[1][kc]);
                            #pragma unroll
                            for (int nf = 0; nf < 2; ++nf) {
                                h8 bs = bfr[nf][kc] * selv[nf][gp * 4 + gl];
                                acc[0][nf] = __builtin_amdgcn_mfma_f32_32x32x16_f16(
                                    a0, bs, acc[0][nf], 0, 0, 0);
                                acc[1][nf] = __builtin_amdgcn_mfma_f32_32x32x16_f16(
                                    a1, bs, acc[1][nf], 0, 0, 0);
                            }
                        }
                    }
                    __builtin_amdgcn_s_setprio(0);
                    if (P < 142) stage_w(P + 2, (2 * kx + gp + 2) % 3);
                }
            }
        }
    }
    // epilogue: + b1, relu, f16, NHWC hr
    // C/D (32x32): col=lane&31, row=(reg&3)+8*(reg>>2)+4*(lane>>5)
    #pragma unroll
    for (int m = 0; m < 2; ++m)
        #pragma unroll
        for (int nf = 0; nf < 2; ++nf) {
            size_t pg = ((size_t)(b * 4096 + yt * 256 + px[nf])) * 128;
            #pragma unroll
            for (int q = 0; q < 4; ++q) {
                int c0 = wm * 64 + m * 32 + q * 8 + kq2 * 4;
                f4 bb = *(const f4*)(b1 + c0);
                h4 hv;
                #pragma unroll
                for (int r = 0; r < 4; ++r)
                    hv[r] = (_Float16)fmaxf(acc[m][nf][q * 4 + r] + bb[r], 0.f);
                *(h4*)(hr + pg + c0) = hv;
            }
        }
}

// ---------------- conv2: switched 1x1 + fused sel2, counted-vmcnt pipe ----
__global__ __launch_bounds__(256, 2) void conv2_k(const _Float16* __restrict__ hr,
        const _Float16* __restrict__ W2r, const float* __restrict__ Wc2,
        const float* __restrict__ bc2, const float* __restrict__ b2,
        const float* __restrict__ x, float* __restrict__ out) {
    __shared__ _Float16 hs[64 * 128];        // [64 px][128 ch] swizzled (16KB)
    __shared__ _Float16 wt[3][8192];         // 3 x 16KB: [256co][32ch slot-XOR]
    __shared__ float wc[1024];               // Wc2 [8][128] (4KB)
    __shared__ float red[2048];              // [64 px][8 g][4 strip] (8KB)
    __shared__ float selw[512];              // [64 px][8 g] (2KB)
    int t = threadIdx.x;
    int bid = blockIdx.x;
    int b = bid >> 6, p0 = (bid & 63) * 64;
    int l = t & 63, w = t >> 6;
    int wm = w >> 1, wn = w & 1;
    int l15 = l & 15, sl = l >> 4;
    const f4 FZ = {0.f, 0.f, 0.f, 0.f};
    f4 acce[8][2], accf[8][2];
    #pragma unroll
    for (int m = 0; m < 8; ++m)
        #pragma unroll
        for (int n = 0; n < 2; ++n) { acce[m][n] = FZ; accf[m][n] = FZ; }

    auto stage_w = [&](int T, int bi) {   // one 16KB chunk via GLD16 (linear)
        const _Float16* srcw = W2r + (size_t)T * 8192 + t * 8;
        _Float16* dw = wt[bi] + t * 8;
        #pragma unroll
        for (int it = 0; it < 4; ++it)
            GLD16(srcw + it * 2048, dw + it * 2048);
    };
    stage_w(0, 0);                        // in flight; drained by prologue syncs
    stage_w(1, 1);

    for (int i = t; i < 1024; i += 256) wc[i] = Wc2[i];
    {   // stage h tile (swizzled)
        int px = t >> 2, qq = t & 3;
        const _Float16* src = hr + (size_t)(b * 4096 + p0 + px) * 128 + qq * 32;
        #pragma unroll
        for (int u = 0; u < 4; ++u)
            *(h8*)(hs + ((px * 128 + qq * 32 + u * 8) ^ ((px & 7) << 3)))
                = *(const h8*)(src + u * 8);
    }
    __syncthreads();                      // publish hs + wc (drains vmcnt too)
    {   // fused sel2: partial logits (4 threads/px x 32 ch)
        int px = t >> 2, qq = t & 3;
        float lg[8] = {0.f,0.f,0.f,0.f,0.f,0.f,0.f,0.f};
        #pragma unroll
        for (int u = 0; u < 4; ++u) {
            h8 v = *(const h8*)(hs + ((px * 128 + qq * 32 + u * 8) ^ ((px & 7) << 3)));
            #pragma unroll
            for (int e = 0; e < 8; ++e) {
                float f = (float)v[e];
                int c = qq * 32 + u * 8 + e;
                #pragma unroll
                for (int g = 0; g < 8; ++g) lg[g] += wc[g * 128 + c] * f;
            }
        }
        #pragma unroll
        for (int g = 0; g < 8; ++g) red[(px * 8 + g) * 4 + qq] = lg[g];
    }
    __syncthreads();
    if (t < 64) {                         // softmax per pixel
        float lg[8]; float m = -1e30f;
        #pragma unroll
        for (int g = 0; g < 8; ++g) {
            lg[g] = red[(t*8+g)*4+0] + red[(t*8+g)*4+1]
                  + red[(t*8+g)*4+2] + red[(t*8+g)*4+3] + bc2[g];
            m = fmaxf(m, lg[g]);
        }
        float sum = 0.f;
        #pragma unroll
        for (int g = 0; g < 8; ++g) { lg[g] = __expf(lg[g] - m); sum += lg[g]; }
        float inv = 1.f / sum;
        #pragma unroll
        for (int g = 0; g < 8; ++g) selw[t * 8 + g] = lg[g] * inv;
    }
    __syncthreads();                      // publish selw
    float selr[8][2];
    #pragma unroll
    for (int g = 0; g < 8; ++g)
        #pragma unroll
        for (int n = 0; n < 2; ++n)
            selr[g][n] = selw[(wn * 32 + n * 16 + l15) * 8 + g];
    int afo[8];
    #pragma unroll
    for (int m = 0; m < 8; ++m) {
        int c = wm * 128 + m * 16 + l15;
        afo[m] = c * 32 + ((sl ^ ((c >> 1) & 3)) * 8);   // involution layout
    }
    #pragma unroll 1
    for (int T = 0; T < 32; ++T) {          // T = g*4 + kchunk
        __builtin_amdgcn_s_barrier();       // raw barrier
        if (T >= 31) {
            asm volatile("s_waitcnt vmcnt(0)" ::: "memory");
        } else {
            asm volatile("s_waitcnt vmcnt(4)" ::: "memory");
        }
        __builtin_amdgcn_sched_barrier(0);
        const _Float16* wp = wt[0] + (size_t)(T % 3) * 8192;
        int kc = (T & 3) * 32;
        h8 bfv[2];
        #pragma unroll
        for (int n = 0; n < 2; ++n) {
            int px = wn * 32 + n * 16 + l15;
            bfv[n] = *(const h8*)(hs + ((px * 128 + kc + sl * 8) ^ ((px & 7) << 3)));
        }
        __builtin_amdgcn_s_setprio(1);
        #pragma unroll
        for (int m = 0; m < 8; ++m) {
            h8 af = *(const h8*)(wp + afo[m]);
            #pragma unroll
            for (int n = 0; n < 2; ++n)
                acce[m][n] = __builtin_amdgcn_mfma_f32_16x16x32_f16(
                    af, bfv[n], acce[m][n], 0, 0, 0);
        }
        __builtin_amdgcn_s_setprio(0);
        if ((T & 3) == 3) {
            int g = T >> 2;
            #pragma unroll
            for (int n = 0; n < 2; ++n)
                #pragma unroll
                for (int m = 0; m < 8; ++m) {
                    accf[m][n] += selr[g][n] * acce[m][n];
                    acce[m][n] = FZ;
                }
        }
        if (T < 30) stage_w(T + 2, (T + 2) % 3);
    }
    // epilogue: + b2 + residual x, fp32 NCHW out
    #pragma unroll
    for (int m = 0; m < 8; ++m) {
        int c0 = wm * 128 + m * 16 + sl * 4;
        f4 bb = *(const f4*)(b2 + c0);
        #pragma unroll
        for (int n = 0; n < 2; ++n) {
            int px = wn * 32 + n * 16 + l15;
            size_t o = (size_t)(b * 256 + c0) * 4096 + p0 + px;
            #pragma unroll
            for (int r = 0; r < 4; ++r)
                out[o + (size_t)r * 4096] = accf[m][n][r] + bb[r] + x[o + (size_t)r * 4096];
        }
    }
}

extern "C" void kernel_launch(void* const* d_in, const int* in_sizes, int n_in,
                              void* d_out, int out_size, void* d_ws, size_t ws_size,
                              hipStream_t stream) {
    const float* x   = (const float*)d_in[0];
    const float* W1  = (const float*)d_in[1];
    const float* b1  = (const float*)d_in[2];
    const float* Wc1 = (const float*)d_in[3];
    const float* bc1 = (const float*)d_in[4];
    const float* W2  = (const float*)d_in[5];
    const float* b2  = (const float*)d_in[6];
    const float* Wc2 = (const float*)d_in[7];
    const float* bc2 = (const float*)d_in[8];
    float* out = (float*)d_out;
    char* ws = (char*)d_ws;
    _Float16* hr  = (_Float16*)(ws);                   // 16,777,216 B
    _Float16* W1r = (_Float16*)(ws + 16777216);        //  4,718,592 B
    _Float16* W2r = (_Float16*)(ws + 21495808);        //    524,288 B
    float* sel1   = (float*)(ws + 22020096);           //  2,097,152 B

    hipLaunchKernelGGL(prep_w_k, dim3(1280), dim3(256), 0, stream, W1, W2, W1r, W2r);
    hipLaunchKernelGGL(prep_x_k, dim3(512), dim3(256), 0, stream, x, Wc1, bc1, sel1);
    hipLaunchKernelGGL(conv1_k, dim3(16, 16), dim3(512), 0, stream, x, W1r, sel1, b1, hr);
    hipLaunchKernelGGL(conv2_k, dim3(1024), dim3(256), 0, stream, hr, W2r, Wc2, bc2, b2, x, out);
}

// Round 18
// 310.582 us; speedup vs baseline: 1.1113x; 1.0784x over previous
//
#include <hip/hip_runtime.h>
#include <hip/hip_bf16.h>
#include <cstdint>

typedef _Float16 h8 __attribute__((ext_vector_type(8)));
typedef _Float16 h4 __attribute__((ext_vector_type(4)));
typedef float    f4 __attribute__((ext_vector_type(4)));
typedef float    fx16 __attribute__((ext_vector_type(16)));

// Dims: B=16, Cin=256, Ch=128, Br=8, H=W=64, 4096 px/image, 65536 px total.
// ws layout:
//   W1r  @ 0           4,718,592 B  (f16 [ci8][tap9][g8][128c][32ch slot-XOR])
//   W2r  @ 4718592       524,288 B  (f16 [g][kc4][256co][32ch slot-XOR])
//   sel1 @ 5242880     2,097,152 B  (f32 [b][g][4096])
//
// LDS involutions: weight tiles: 16B slot s at row r -> s ^ ((r>>1)&3).
//                  hs: h-index ^ ((px&7)<<3)  (quad = slot^(px&7), uniform).
//
// Fused kernel = conv1 (FROZEN R16 main loop) + in-LDS h + fused sel2 +
// conv2 GEMM (R13's verified reg-staged 2-buffer protocol) + residual out.
// LDS arena (halves): [0..49152) wt[3] (conv1) -> hs[0..32768) + w2buf
// [32768..49152) (conv2); [49152..61448) xs (conv1) -> wc2/red/selw (sel2).
// Alias ledger: wt last read at phase 143; post-loop __syncthreads; h-write
// and wc2 copy; __syncthreads; logits(red); __syncthreads; softmax(selw) +
// write_w(0)+load_w(1); __syncthreads; GEMM loop (R13 protocol: write_w
// targets the buffer whose last readers finished before the previous sync).

#define GLD16(src, dst) __builtin_amdgcn_global_load_lds( \
    (const __attribute__((address_space(1))) void*)(src), \
    (__attribute__((address_space(3))) void*)(dst), 16, 0, 0)

// ---------------- prep_w: fp32 -> f16 repack, output-major ----------------
__global__ __launch_bounds__(256) void prep_w_k(const float* __restrict__ W1,
        const float* __restrict__ W2, _Float16* __restrict__ W1r,
        _Float16* __restrict__ W2r) {
    int o8 = blockIdx.x * 256 + threadIdx.x;   // one h8 output group per thread
    if (o8 < 294912) {
        int sq = o8 & 3;
        int c  = (o8 >> 2) & 127;
        int g  = (o8 >> 9) & 7;
        int tk = o8 >> 12;                 // cik*9 + tap
        int tap = tk % 9, cik = tk / 9;
        int s = sq ^ ((c >> 1) & 3);
        int ci0 = cik * 32 + s * 8;
        const float* src = W1 + ((size_t)(g * 128 + c) * 256 + ci0) * 9 + tap;
        h8 v;
        #pragma unroll
        for (int e = 0; e < 8; ++e) v[e] = (_Float16)src[e * 9];
        *(h8*)(W1r + (size_t)o8 * 8) = v;
    } else {
        int ow = o8 - 294912;              // W2r h8 groups: 32768
        int sq = ow & 3;                   // physical 16B slot
        int co = (ow >> 2) & 255;
        int kc = (ow >> 10) & 3;
        int g  = ow >> 12;
        int s = sq ^ ((co >> 1) & 3);      // logical 8-half group (involution)
        const float* src = W2 + ((size_t)(g * 256 + co) * 128) + kc * 32 + s * 8;
        h8 v;
        #pragma unroll
        for (int e = 0; e < 8; ++e) v[e] = (_Float16)src[e];
        *(h8*)(W2r + (size_t)ow * 8) = v;
    }
}

// ---------------- prep_x: sel1 softmax, 2 threads/px ----------------
__global__ __launch_bounds__(256) void prep_x_k(const float* __restrict__ x,
        const float* __restrict__ Wc1, const float* __restrict__ bc1,
        float* __restrict__ sel1) {
    __shared__ float wc[2048];            // Wc1 [8][256]
    __shared__ float red[1024];           // [128 px][8 g] partial from upper half
    int t = threadIdx.x;
    for (int i = t; i < 2048; i += 256) wc[i] = Wc1[i];
    __syncthreads();
    int pxl = t & 127, ch = t >> 7;       // ch: c-half 0/1
    int pix = blockIdx.x * 128 + pxl;
    int b = pix >> 12, p = pix & 4095;
    const float* xp = x + (size_t)b * 1048576 + (size_t)ch * 524288 + p;
    float lg[8] = {0.f,0.f,0.f,0.f,0.f,0.f,0.f,0.f};
    for (int c = 0; c < 128; ++c) {
        float v = fmaxf(xp[(size_t)c * 4096], 0.f);
        #pragma unroll
        for (int g = 0; g < 8; ++g) lg[g] += wc[g * 256 + ch * 128 + c] * v;
    }
    if (ch)
        #pragma unroll
        for (int g = 0; g < 8; ++g) red[pxl * 8 + g] = lg[g];
    __syncthreads();
    if (!ch) {
        float m = -1e30f;
        #pragma unroll
        for (int g = 0; g < 8; ++g) {
            lg[g] += red[pxl * 8 + g] + bc1[g];
            m = fmaxf(m, lg[g]);
        }
        float sum = 0.f;
        #pragma unroll
        for (int g = 0; g < 8; ++g) { lg[g] = __expf(lg[g] - m); sum += lg[g]; }
        float inv = 1.f / sum;
        #pragma unroll
        for (int g = 0; g < 8; ++g)
            sel1[(size_t)(b * 8 + g) * 4096 + p] = lg[g] * inv;
    }
}

// -------- fused conv1 (frozen R16) + sel2 + conv2 + residual --------------
__global__ __launch_bounds__(512) void conv1_k(const float* __restrict__ x,
        const _Float16* __restrict__ W1r, const _Float16* __restrict__ W2r,
        const float* __restrict__ sel1, const float* __restrict__ Wc2,
        const float* __restrict__ bc2, const float* __restrict__ b1,
        const float* __restrict__ b2, float* __restrict__ out) {
    __shared__ _Float16 arena[61448];
    _Float16* xs = arena + 49152;         // conv1 xs [6r][64c][32ch] + zero @12288
    int t = threadIdx.x;
    int b = blockIdx.y, yt = blockIdx.x;  // yt: group of 4 output rows
    int y0 = yt * 4;
    int w = t >> 6, l = t & 63;
    int wm = w >> 2, wn = w & 3;          // wm: 64-ch half, wn: output row (64px)
    int l31 = l & 31, kq2 = l >> 5;
    if (t < 8) xs[12288 + t] = (_Float16)0.f;   // zero slot

    fx16 acc[2][2];                       // [m][nf]
    #pragma unroll
    for (int m = 0; m < 2; ++m)
        #pragma unroll
        for (int n = 0; n < 2; ++n)
            #pragma unroll
            for (int e = 0; e < 16; ++e) acc[m][n][e] = 0.f;

    auto stage_w = [&](int P, int bi) {   // one 4-expert chunk (32 KB)
        const _Float16* srcw = W1r + (size_t)P * 16384 + t * 8;
        _Float16* dw = arena + bi * 16384 + t * 8;
        #pragma unroll
        for (int it = 0; it < 4; ++it)
            GLD16(srcw + it * 4096, dw + it * 4096);
    };

    // lane constants (R6-identical)
    int px[2];
    #pragma unroll
    for (int nf = 0; nf < 2; ++nf) px[nf] = wn * 64 + nf * 32 + l31;
    bool e0 = (l31 == 0), e63 = (l31 == 31);
    int afo[2][2];
    #pragma unroll
    for (int m = 0; m < 2; ++m)
        #pragma unroll
        for (int kc = 0; kc < 2; ++kc) {
            int c = wm * 64 + m * 32 + l31;
            afo[m][kc] = c * 32 + (((kc * 2 + kq2) ^ ((c >> 1) & 3)) * 8);
        }
    int ba[2][3][2];
    #pragma unroll
    for (int nf = 0; nf < 2; ++nf)
        #pragma unroll
        for (int kx = 0; kx < 3; ++kx) {
            int rz = px[nf] + kx - 1;
            #pragma unroll
            for (int kc = 0; kc < 2; ++kc)
                ba[nf][kx][kc] = rz * 32 + (((kc * 2 + kq2) ^ ((rz >> 1) & 3)) * 8);
        }
    h8 selv[2];
    #pragma unroll
    for (int nf = 0; nf < 2; ++nf)
        #pragma unroll
        for (int g = 0; g < 8; ++g)
            selv[nf][g] = (_Float16)sel1[(size_t)(b * 8 + g) * 4096 + yt * 256 + px[nf]];

    h8 bfr[2][2];                         // B-frags for current tap [nf][kc]

    stage_w(0, 0);
    stage_w(1, 1);

    #pragma unroll 1
    for (int ci = 0; ci < 8; ++ci) {
        if (t < 384) {
            int r = t >> 6, col = t & 63;
            int rc = r * 64 + col;
            int yi = y0 - 1 + r;
            _Float16* dx = xs + rc * 32;
            int rx = (rc >> 1) & 3;
            if (yi >= 0 && yi < 64) {
                const float* xp = x + ((size_t)(b * 256 + ci * 32)) * 4096 + yi * 64 + col;
                float v[32];
                #pragma unroll
                for (int c2 = 0; c2 < 32; ++c2)
                    v[c2] = fmaxf(xp[(size_t)c2 * 4096], 0.f);
                #pragma unroll
                for (int qq = 0; qq < 4; ++qq) {
                    h8 hv;
                    #pragma unroll
                    for (int e = 0; e < 8; ++e) hv[e] = (_Float16)v[qq * 8 + e];
                    *(h8*)(dx + (qq ^ rx) * 8) = hv;   // involution: read undoes it
                }
            } else {
                const h8 HZ = {};
                #pragma unroll
                for (int qq = 0; qq < 4; ++qq)
                    *(h8*)(dx + (qq ^ rx) * 8) = HZ;
            }
        }
        __syncthreads();                  // publish xs (full drain, 1x per ci)
        #pragma unroll 1
        for (int ky = 0; ky < 3; ++ky) {
            #pragma unroll
            for (int kx = 0; kx < 3; ++kx) {
                int tap = ci * 9 + ky * 3 + kx;
                #pragma unroll
                for (int nf = 0; nf < 2; ++nf)
                    #pragma unroll
                    for (int kc = 0; kc < 2; ++kc) {
                        int a = ba[nf][kx][kc] + ky * 2048;
                        if (kx == 0 && nf == 0) a = e0 ? 12288 : a;
                        if (kx == 2 && nf == 1) a = e63 ? 12288 : a;
                        bfr[nf][kc] = *(const h8*)(xs + a);
                    }
                #pragma unroll
                for (int gp = 0; gp < 2; ++gp) {
                    int P = tap * 2 + gp;
                    __builtin_amdgcn_s_barrier();      // raw barrier, no drain
                    if (P >= 143) {
                        asm volatile("s_waitcnt vmcnt(0)" ::: "memory");
                    } else {
                        asm volatile("s_waitcnt vmcnt(4)" ::: "memory");
                    }
                    __builtin_amdgcn_sched_barrier(0);
                    const _Float16* wp = arena + ((2 * kx + gp) % 3) * 16384;
                    __builtin_amdgcn_s_setprio(1);
                    #pragma unroll
                    for (int gl = 0; gl < 4; ++gl) {
                        #pragma unroll
                        for (int kc = 0; kc < 2; ++kc) {
                            h8 a0 = *(const h8*)(wp + gl * 4096 + afo[0][kc]);
                            h8 a1 = *(const h8*)(wp + gl * 4096 + afo[1][kc]);
                            #pragma unroll
                            for (int nf = 0; nf < 2; ++nf) {
                                h8 bs = bfr[nf][kc] * selv[nf][gp * 4 + gl];
                                acc[0][nf] = __builtin_amdgcn_mfma_f32_32x32x16_f16(
                                    a0, bs, acc[0][nf], 0, 0, 0);
                                acc[1][nf] = __builtin_amdgcn_mfma_f32_32x32x16_f16(
                                    a1, bs, acc[1][nf], 0, 0, 0);
                            }
                        }
                    }
                    __builtin_amdgcn_s_setprio(0);
                    if (P < 142) stage_w(P + 2, (2 * kx + gp + 2) % 3);
                }
            }
        }
    }
    // ---------------- fused tail ----------------
    __syncthreads();                      // wt + xs dead; vm/lgkm drained
    float* WC2f  = (float*)(arena + 49152);   // 1024 f32
    float* REDf  = (float*)(arena + 51200);   // 2048 f32 [256px][8g]
    float* SELWf = (float*)(arena + 55296);   // 2048 f32 [256px][8g]
    _Float16* w2b0 = arena + 32768;           // 2 x 16KB W2 chunk bufs
    _Float16* w2b1 = arena + 40960;
    // write h (bias+relu, f16) into hs = arena[0..32768), involution ^((px&7)<<3)
    // C/D (32x32): col=lane&31 -> px; row=(reg&3)+8*(reg>>2)+4*(lane>>5) -> ch
    #pragma unroll
    for (int m = 0; m < 2; ++m)
        #pragma unroll
        for (int nf = 0; nf < 2; ++nf) {
            int pxv = px[nf];
            #pragma unroll
            for (int q = 0; q < 4; ++q) {
                int c0 = wm * 64 + m * 32 + q * 8 + kq2 * 4;
                f4 bb = *(const f4*)(b1 + c0);
                h4 hv;
                #pragma unroll
                for (int r = 0; r < 4; ++r)
                    hv[r] = (_Float16)fmaxf(acc[m][nf][q * 4 + r] + bb[r], 0.f);
                int H = pxv * 128 + c0;
                *(h4*)(arena + (H ^ ((pxv & 7) << 3))) = hv;
            }
        }
    if (t < 512) { WC2f[t] = Wc2[t]; WC2f[t + 512] = Wc2[t + 512]; }
    // conv2 reg staging (R13 protocol); chunk = [256co][32ch] = 8192 halves
    h8 wr[2];
    auto load_w2 = [&](int T) {
        const _Float16* srcw = W2r + (size_t)T * 8192;
        wr[0] = *(const h8*)(srcw + (size_t)t * 8);
        wr[1] = *(const h8*)(srcw + (size_t)(512 + t) * 8);
    };
    auto write_w2 = [&](_Float16* dst) {
        *(h8*)(dst + t * 8) = wr[0];
        *(h8*)(dst + (512 + t) * 8) = wr[1];
    };
    load_w2(0);
    __syncthreads();                      // publish hs + wc2
    {   // sel2 logits: 2 threads/px, 64 ch each
        int px2 = t >> 1, half = t & 1;
        float lg[8] = {0.f,0.f,0.f,0.f,0.f,0.f,0.f,0.f};
        #pragma unroll
        for (int u = 0; u < 8; ++u) {
            int H = px2 * 128 + half * 64 + u * 8;
            h8 v = *(const h8*)(arena + (H ^ ((px2 & 7) << 3)));
            #pragma unroll
            for (int e = 0; e < 8; ++e) {
                float f = (float)v[e];
                int c = half * 64 + u * 8 + e;
                #pragma unroll
                for (int g = 0; g < 8; ++g) lg[g] += WC2f[g * 128 + c] * f;
            }
        }
        if (half)
            #pragma unroll
            for (int g = 0; g < 8; ++g) REDf[px2 * 8 + g] = lg[g];
        __syncthreads();
        if (!half) {                      // softmax, one px per (even) thread
            float m2 = -1e30f;
            #pragma unroll
            for (int g = 0; g < 8; ++g) {
                lg[g] += REDf[px2 * 8 + g] + bc2[g];
                m2 = fmaxf(m2, lg[g]);
            }
            float sum = 0.f;
            #pragma unroll
            for (int g = 0; g < 8; ++g) { lg[g] = __expf(lg[g] - m2); sum += lg[g]; }
            float inv = 1.f / sum;
            #pragma unroll
            for (int g = 0; g < 8; ++g) SELWf[px2 * 8 + g] = lg[g] * inv;
        }
    }
    write_w2(w2b0);                       // w2b0 region dead since post-loop sync
    load_w2(1);
    __syncthreads();                      // publish selw + w2b0
    // GEMM: 8 waves = wm2(co-half 128) x wn4(px 64); 16x16x32; sel-scaled B
    int sl = l >> 4, l15g = l & 15;
    int pg[4];
    #pragma unroll
    for (int n = 0; n < 4; ++n) pg[n] = wn * 64 + n * 16 + l15g;
    h8 selr[4];                           // [n] element g, f16
    #pragma unroll
    for (int n = 0; n < 4; ++n)
        #pragma unroll
        for (int g = 0; g < 8; ++g)
            selr[n][g] = (_Float16)SELWf[pg[n] * 8 + g];
    int afo2[8];
    #pragma unroll
    for (int m = 0; m < 8; ++m) {
        int co = wm * 128 + m * 16 + l15g;
        afo2[m] = co * 32 + ((sl ^ ((co >> 1) & 3)) * 8);
    }
    f4 acc2[8][4];
    #pragma unroll
    for (int m = 0; m < 8; ++m)
        #pragma unroll
        for (int n = 0; n < 4; ++n) acc2[m][n] = (f4){0.f, 0.f, 0.f, 0.f};
    #pragma unroll 1
    for (int T = 0; T < 32; ++T) {        // T = g*4 + kc
        if (T < 31) load_w2(T + 1);
        __syncthreads();                  // publish w2buf[T&1]
        const _Float16* wp = (T & 1) ? w2b1 : w2b0;
        int kc = (T & 3) * 32;
        int g = T >> 2;
        h8 bsv[4];
        #pragma unroll
        for (int n = 0; n < 4; ++n) {
            int H = pg[n] * 128 + kc + sl * 8;
            h8 bv = *(const h8*)(arena + (H ^ ((pg[n] & 7) << 3)));
            bsv[n] = bv * selr[n][g];     // sel-scaled B
        }
        __builtin_amdgcn_s_setprio(1);
        #pragma unroll
        for (int m = 0; m < 8; ++m) {
            h8 af = *(const h8*)(wp + afo2[m]);
            #pragma unroll
            for (int n = 0; n < 4; ++n)
                acc2[m][n] = __builtin_amdgcn_mfma_f32_16x16x32_f16(
                    af, bsv[n], acc2[m][n], 0, 0, 0);
        }
        __builtin_amdgcn_s_setprio(0);
        if (T < 31) write_w2((T & 1) ? w2b0 : w2b1);
    }
    // epilogue: + b2 + residual x, fp32 NCHW out
    // 16x16 C/D: col = l15 -> px, row = sl*4 + r -> co
    #pragma unroll
    for (int m = 0; m < 8; ++m) {
        int c0 = wm * 128 + m * 16 + sl * 4;
        f4 bb = *(const f4*)(b2 + c0);
        #pragma unroll
        for (int n = 0; n < 4; ++n) {
            size_t o = (size_t)(b * 256 + c0) * 4096 + yt * 256 + pg[n];
            #pragma unroll
            for (int r = 0; r < 4; ++r)
                out[o + (size_t)r * 4096] = acc2[m][n][r] + bb[r] + x[o + (size_t)r * 4096];
        }
    }
}

extern "C" void kernel_launch(void* const* d_in, const int* in_sizes, int n_in,
                              void* d_out, int out_size, void* d_ws, size_t ws_size,
                              hipStream_t stream) {
    const float* x   = (const float*)d_in[0];
    const float* W1  = (const float*)d_in[1];
    const float* b1  = (const float*)d_in[2];
    const float* Wc1 = (const float*)d_in[3];
    const float* bc1 = (const float*)d_in[4];
    const float* W2  = (const float*)d_in[5];
    const float* b2  = (const float*)d_in[6];
    const float* Wc2 = (const float*)d_in[7];
    const float* bc2 = (const float*)d_in[8];
    float* out = (float*)d_out;
    char* ws = (char*)d_ws;
    _Float16* W1r = (_Float16*)(ws);                   //  4,718,592 B
    _Float16* W2r = (_Float16*)(ws + 4718592);         //    524,288 B
    float* sel1   = (float*)(ws + 5242880);            //  2,097,152 B

    hipLaunchKernelGGL(prep_w_k, dim3(1280), dim3(256), 0, stream, W1, W2, W1r, W2r);
    hipLaunchKernelGGL(prep_x_k, dim3(512), dim3(256), 0, stream, x, Wc1, bc1, sel1);
    hipLaunchKernelGGL(conv1_k, dim3(16, 16), dim3(512), 0, stream,
                       x, W1r, W2r, sel1, Wc2, bc2, b1, b2, out);
}